// Round 2
// baseline (199.556 us; speedup 1.0000x reference)
//
#include <hip/hip_runtime.h>
#include <hip/hip_bf16.h>

#define SEQ 2048

typedef short s4v __attribute__((ext_vector_type(4)));
typedef float f32x4 __attribute__((ext_vector_type(4)));
typedef short s8v __attribute__((ext_vector_type(8)));

using bf16 = __hip_bfloat16;

__device__ __forceinline__ float wred_sum(float v){
#pragma unroll
  for (int i = 1; i < 64; i <<= 1) v += __shfl_xor(v, i, 64);
  return v;
}

__device__ __forceinline__ float wred_max(float v){
#pragma unroll
  for (int i = 1; i < 64; i <<= 1) v = fmaxf(v, __shfl_xor(v, i, 64));
  return v;
}

// Detect whether a "float" input buffer is really f32 (1) or bf16 (0).
// Reads the first 128 halfwords as bf16. If the buffer holds f32, half of
// those are f32 mantissa halves -> uniform random exponents -> max >> 1e3.
// If bf16 N(0,1) data, max < ~6. Block-uniform result.
__device__ __forceinline__ int detect_f32(const void* xraw){
  const unsigned short* p = (const unsigned short*)xraw;
  const int lane = threadIdx.x & 63;
  float mx = 0.f;
#pragma unroll
  for (int i = 0; i < 2; ++i){
    unsigned u = ((unsigned)p[lane * 2 + i]) << 16;
    float f = fabsf(__uint_as_float(u));
    if (!(f < 1e30f)) f = 1e30f;       // NaN/Inf -> large
    mx = fmaxf(mx, f);
  }
  mx = wred_max(mx);
  return mx > 1e3f ? 1 : 0;
}

template<int F32>
__device__ __forceinline__ float ldf(const void* p, int i){
  if constexpr (F32) return ((const float*)p)[i];
  else return __bfloat162float(((const bf16*)p)[i]);
}

__device__ __forceinline__ unsigned short f2bu(float f){
  union { float f; unsigned u; } v; v.f = f;
  return (unsigned short)((v.u + 0x7FFFu + ((v.u >> 16) & 1u)) >> 16);
}

// ---------------- Kernel A: LN1 + QKV projection (wave per row) ----------------
template<int F32>
__device__ __forceinline__ void ln_qkv_body(
    const void* x,
    const void* Wq, const void* bq,
    const void* Wk, const void* bk,
    const void* Wv, const void* bv,
    const void* ln1w, const void* ln1b,
    float* x1f, bf16* Qb, bf16* Kb, bf16* Vb, float (*xs)[64])
{
  const int w = threadIdx.x >> 6, lane = threadIdx.x & 63;
  const int row = blockIdx.x * 4 + w;                 // 0..8191 (= b*2048+s)
  float xv = ldf<F32>(x, row * 64 + lane);
  float mu = wred_sum(xv) * 0.015625f;
  float dv = xv - mu;
  float var = wred_sum(dv * dv) * 0.015625f;
  float x1 = dv * rsqrtf(var + 1e-5f) * ldf<F32>(ln1w, lane) + ldf<F32>(ln1b, lane);
  x1f[(size_t)row * 64 + lane] = x1;
  xs[w][lane] = x1;
  __syncthreads();
  float q = ldf<F32>(bq, lane);
  float k = ldf<F32>(bk, lane);
  float v = ldf<F32>(bv, lane);
#pragma unroll 16
  for (int d = 0; d < 64; ++d){
    float xd = xs[w][d];                              // LDS broadcast
    q += xd * ldf<F32>(Wq, d * 64 + lane);            // contiguous per d
    k += xd * ldf<F32>(Wk, d * 64 + lane);
    v += xd * ldf<F32>(Wv, d * 64 + lane);
  }
  Qb[(size_t)row * 64 + lane] = __float2bfloat16(q);
  Kb[(size_t)row * 64 + lane] = __float2bfloat16(k);
  Vb[(size_t)row * 64 + lane] = __float2bfloat16(v);
}

__global__ __launch_bounds__(256) void k_ln_qkv(
    const void* x, const void* Wq, const void* bq, const void* Wk, const void* bk,
    const void* Wv, const void* bv, const void* ln1w, const void* ln1b,
    float* x1f, bf16* Qb, bf16* Kb, bf16* Vb)
{
  __shared__ float xs[4][64];
  if (detect_f32(x))
    ln_qkv_body<1>(x, Wq, bq, Wk, bk, Wv, bv, ln1w, ln1b, x1f, Qb, Kb, Vb, xs);
  else
    ln_qkv_body<0>(x, Wq, bq, Wk, bk, Wv, bv, ln1w, ln1b, x1f, Qb, Kb, Vb, xs);
}

// ---------------- Kernel A2: transpose V -> Vt[b][h][d][s] (bf16) ----------------
__global__ __launch_bounds__(256) void k_vt(const bf16* __restrict__ Vb, bf16* __restrict__ Vt)
{
  const int idx = blockIdx.x;            // 256 blocks
  const int sc = idx & 7;                // s-chunk (8 x 256)
  const int bh = idx >> 3;               // b*8+h, 0..31
  const int s0 = sc * 256;
  const int b = bh >> 3, h = bh & 7;
  __shared__ unsigned short tile[256][9];   // pad to break bank alignment
  const int t = threadIdx.x;
  s8v vrow = *reinterpret_cast<const s8v*>(Vb + ((size_t)(b * SEQ + s0 + t)) * 64 + h * 8);
#pragma unroll
  for (int i = 0; i < 8; ++i) tile[t][i] = (unsigned short)vrow[i];
  __syncthreads();
  const int d = t >> 5, j = t & 31;      // d 0..7, j 0..31 (8 s-values each)
  unsigned short tmp[8];
#pragma unroll
  for (int i = 0; i < 8; ++i) tmp[i] = tile[j * 8 + i][d];
  uint4 o;
  o.x = (unsigned)tmp[0] | ((unsigned)tmp[1] << 16);
  o.y = (unsigned)tmp[2] | ((unsigned)tmp[3] << 16);
  o.z = (unsigned)tmp[4] | ((unsigned)tmp[5] << 16);
  o.w = (unsigned)tmp[6] | ((unsigned)tmp[7] << 16);
  *reinterpret_cast<uint4*>(Vt + ((size_t)(bh * 8 + d)) * SEQ + s0 + j * 8) = o;
}

// ---------------- Kernel B: flash attention, all heads per block ----------------
// block = 512 thr (8 waves, wave w = head w); 16 queries per block.
// S^T = K_tile . Q^T via mfma_16x16x16_bf16 (dk=8 padded to 16).
// D-layout of S^T (k=4g+r, q=lane&15) == B-operand layout of PV -> no transpose.
__global__ __launch_bounds__(512) void k_attn(
    const bf16* __restrict__ Qb, const bf16* __restrict__ Kb, const bf16* __restrict__ Vt,
    const int* __restrict__ mask, float* __restrict__ ctxf)
{
  const int b  = blockIdx.x >> 7;
  const int q0 = (blockIdx.x & 127) * 16;
  const int h  = threadIdx.x >> 6;
  const int lane = threadIdx.x & 63;
  const int g = lane >> 4, qi = lane & 15;

  __shared__ __align__(16) int msk[2][16][36];   // mask tile, rows 144B (16-aligned)

  s4v qf = {0, 0, 0, 0};
  if (g < 2) qf = *reinterpret_cast<const s4v*>(Qb + ((size_t)(b * SEQ + q0 + qi)) * 64 + h * 8 + 4 * g);

  const bf16* kbase = Kb + (size_t)b * SEQ * 64 + h * 8 + 4 * g;          // deref when g<2
  const bf16* vbase = Vt + ((size_t)((b * 8 + h) * 8 + qi)) * SEQ;        // deref when qi<8

  const float SCALE = 1.4426950408889634f * 0.35355339059327373f;  // log2(e)/sqrt(8)
  float m_run = -3.0e38f, s_run = 0.f;
  f32x4 acc = {0.f, 0.f, 0.f, 0.f};
  const f32x4 zf = {0.f, 0.f, 0.f, 0.f};

  const int t = threadIdx.x;
  const int* mrow = mask + (size_t)b * SEQ * SEQ + (size_t)(q0 + (t >> 5)) * SEQ + (t & 31);

  for (int kt = 0; kt < SEQ / 32; ++kt){
    const int k0 = kt * 32;
    msk[kt & 1][t >> 5][t & 31] = mrow[k0];        // stage 16x32 mask ints, coalesced
    __syncthreads();
#pragma unroll
    for (int hf = 0; hf < 2; ++hf){
      const int kb = k0 + hf * 16;
      s4v kf = {0, 0, 0, 0};
      if (g < 2) kf = *reinterpret_cast<const s4v*>(kbase + (size_t)(kb + qi) * 64);
      f32x4 st = __builtin_amdgcn_mfma_f32_16x16x16bf16_1k(kf, qf, zf, 0, 0, 0);
      const int4 mm = *reinterpret_cast<const int4*>(&msk[kt & 1][qi][hf * 16 + 4 * g]);
      float sc0 = (mm.x == 1) ? -1.44e9f : st[0] * SCALE;   // log2-domain scores
      float sc1 = (mm.y == 1) ? -1.44e9f : st[1] * SCALE;
      float sc2 = (mm.z == 1) ? -1.44e9f : st[2] * SCALE;
      float sc3 = (mm.w == 1) ? -1.44e9f : st[3] * SCALE;
      float tm = fmaxf(fmaxf(sc0, sc1), fmaxf(sc2, sc3));
      tm = fmaxf(tm, __shfl_xor(tm, 16, 64));
      tm = fmaxf(tm, __shfl_xor(tm, 32, 64));
      const float mnew = fmaxf(m_run, tm);
      const float corr = exp2f(m_run - mnew);
      const float p0 = exp2f(sc0 - mnew);
      const float p1 = exp2f(sc1 - mnew);
      const float p2 = exp2f(sc2 - mnew);
      const float p3 = exp2f(sc3 - mnew);
      float ts = (p0 + p1) + (p2 + p3);
      ts += __shfl_xor(ts, 16, 64);
      ts += __shfl_xor(ts, 32, 64);
      s_run = s_run * corr + ts;
      m_run = mnew;
      s4v pf;
      pf[0] = (short)f2bu(p0); pf[1] = (short)f2bu(p1);
      pf[2] = (short)f2bu(p2); pf[3] = (short)f2bu(p3);
      s4v vf = {0, 0, 0, 0};
      if (qi < 8) vf = *reinterpret_cast<const s4v*>(vbase + kb + 4 * g);
      acc = acc * corr;
      acc = __builtin_amdgcn_mfma_f32_16x16x16bf16_1k(vf, pf, acc, 0, 0, 0);
    }
  }
  if (g < 2){
    const float inv = 1.f / s_run;
    float4 o;
    o.x = acc[0] * inv; o.y = acc[1] * inv; o.z = acc[2] * inv; o.w = acc[3] * inv;
    *reinterpret_cast<float4*>(ctxf + ((size_t)((b * 8 + h) * SEQ + q0 + qi)) * 8 + 4 * g) = o;
  }
}

// ---------------- Kernel C: Wo + residuals + LN2 + FFN (wave per row) ----------------
template<int F32>
__device__ __forceinline__ void ffn_body(
    const float* ctxf, const float* x1f,
    const void* Wo, const void* bo, const void* W1, const void* b1,
    const void* W2, const void* b2, const void* ln2w, const void* ln2b,
    void* out, float (*cs)[64], float (*x3s)[64], float (*gs)[256])
{
  const int w = threadIdx.x >> 6, c = threadIdx.x & 63;
  const int row = blockIdx.x * 4 + w;
  // ctx.reshape(B,S,D) of contiguous [B,H,S,dk] == flat view: ctx_resh[b,r,c]=ctxf[row*64+c]
  float ctxv = ctxf[(size_t)row * 64 + c];
  float x1v  = x1f[(size_t)row * 64 + c];
  cs[w][c] = ctxv;
  __syncthreads();
  float proj = ldf<F32>(bo, c);
#pragma unroll 8
  for (int d = 0; d < 64; ++d) proj += cs[w][d] * ldf<F32>(Wo, d * 64 + c);
  // attn_out = ctx@Wo + bo + x1 ; x2 = x1 + attn_out (faithful double residual)
  float x2 = 2.f * x1v + proj;
  float mu = wred_sum(x2) * 0.015625f;
  float dv = x2 - mu;
  float var = wred_sum(dv * dv) * 0.015625f;
  float x3 = dv * rsqrtf(var + 1e-5f) * ldf<F32>(ln2w, c) + ldf<F32>(ln2b, c);
  x3s[w][c] = x3;
  __syncthreads();
#pragma unroll
  for (int cc = 0; cc < 4; ++cc){
    const int col = cc * 64 + c;
    float h1 = ldf<F32>(b1, col);
#pragma unroll 8
    for (int d = 0; d < 64; ++d) h1 += x3s[w][d] * ldf<F32>(W1, d * 256 + col);
    gs[w][col] = 0.5f * h1 * (1.f + erff(h1 * 0.70710678f));   // exact gelu
  }
  __syncthreads();
  float ff = ldf<F32>(b2, c);
#pragma unroll 8
  for (int f = 0; f < 256; ++f) ff += gs[w][f] * ldf<F32>(W2, f * 64 + c);
  float res = x2 + ff;
  if constexpr (F32) ((float*)out)[(size_t)row * 64 + c] = res;
  else               ((bf16*)out)[(size_t)row * 64 + c] = __float2bfloat16(res);
}

__global__ __launch_bounds__(256) void k_ffn(
    const void* xprobe,
    const float* ctxf, const float* x1f,
    const void* Wo, const void* bo, const void* W1, const void* b1,
    const void* W2, const void* b2, const void* ln2w, const void* ln2b,
    void* out)
{
  __shared__ float cs[4][64];
  __shared__ float x3s[4][64];
  __shared__ float gs[4][256];
  if (detect_f32(xprobe))
    ffn_body<1>(ctxf, x1f, Wo, bo, W1, b1, W2, b2, ln2w, ln2b, out, cs, x3s, gs);
  else
    ffn_body<0>(ctxf, x1f, Wo, bo, W1, b1, W2, b2, ln2w, ln2b, out, cs, x3s, gs);
}

extern "C" void kernel_launch(void* const* d_in, const int* in_sizes, int n_in,
                              void* d_out, int out_size, void* d_ws, size_t ws_size,
                              hipStream_t stream)
{
  (void)in_sizes; (void)n_in; (void)out_size; (void)ws_size;
  const void* x    = d_in[0];
  const int*  mask = (const int*)d_in[1];
  const void* Wq = d_in[2];
  const void* bq = d_in[3];
  const void* Wk = d_in[4];
  const void* bk = d_in[5];
  const void* Wv = d_in[6];
  const void* bv = d_in[7];
  const void* Wo = d_in[8];
  const void* bo = d_in[9];
  const void* W1 = d_in[10];
  const void* b1 = d_in[11];
  const void* W2 = d_in[12];
  const void* b2 = d_in[13];
  const void* ln1w = d_in[14];
  const void* ln1b = d_in[15];
  const void* ln2w = d_in[16];
  const void* ln2b = d_in[17];

  char* ws = (char*)d_ws;
  float* x1f = (float*)(ws + 0);              // 2 MB  [B][S][64] f32
  bf16*  Qb  = (bf16*)(ws + (2u << 20));      // 1 MB  [B][S][64] bf16
  bf16*  Kb  = (bf16*)(ws + (3u << 20));      // 1 MB
  bf16*  Vb  = (bf16*)(ws + (4u << 20));      // 1 MB
  bf16*  Vt  = (bf16*)(ws + (5u << 20));      // 1 MB  [B][H][8][S] bf16
  float* ctxf= (float*)(ws + (6u << 20));     // 2 MB  [B][H][S][8] f32

  k_ln_qkv<<<2048, 256, 0, stream>>>(x, Wq, bq, Wk, bk, Wv, bv, ln1w, ln1b, x1f, Qb, Kb, Vb);
  k_vt<<<256, 256, 0, stream>>>(Vb, Vt);
  k_attn<<<512, 512, 0, stream>>>(Qb, Kb, Vt, mask, ctxf);
  k_ffn<<<2048, 256, 0, stream>>>(x, ctxf, x1f, Wo, bo, W1, b1, W2, b2, ln2w, ln2b, d_out);
}

// Round 3
// 197.906 us; speedup vs baseline: 1.0083x; 1.0083x over previous
//
#include <hip/hip_runtime.h>
#include <hip/hip_bf16.h>

#define SEQ 2048

typedef short s4v __attribute__((ext_vector_type(4)));
typedef float f32x4 __attribute__((ext_vector_type(4)));
typedef short s8v __attribute__((ext_vector_type(8)));

using bf16 = __hip_bfloat16;

__device__ __forceinline__ float wred_sum(float v){
#pragma unroll
  for (int i = 1; i < 64; i <<= 1) v += __shfl_xor(v, i, 64);
  return v;
}

__device__ __forceinline__ float wred_max(float v){
#pragma unroll
  for (int i = 1; i < 64; i <<= 1) v = fmaxf(v, __shfl_xor(v, i, 64));
  return v;
}

// Detect whether a "float" input buffer is really f32 (1) or bf16 (0).
__device__ __forceinline__ int detect_f32(const void* xraw){
  const unsigned short* p = (const unsigned short*)xraw;
  const int lane = threadIdx.x & 63;
  float mx = 0.f;
#pragma unroll
  for (int i = 0; i < 2; ++i){
    unsigned u = ((unsigned)p[lane * 2 + i]) << 16;
    float f = fabsf(__uint_as_float(u));
    if (!(f < 1e30f)) f = 1e30f;       // NaN/Inf -> large
    mx = fmaxf(mx, f);
  }
  mx = wred_max(mx);
  return mx > 1e3f ? 1 : 0;
}

template<int F32>
__device__ __forceinline__ float ldf(const void* p, int i){
  if constexpr (F32) return ((const float*)p)[i];
  else return __bfloat162float(((const bf16*)p)[i]);
}

// log2(e)/sqrt(dk) folded into Q at projection time
#define QSCALE 0.5101129340352065f

// ---------------- Kernel A: LN1 + QKV projection (wave per row) ----------------
template<int F32>
__device__ __forceinline__ void ln_qkv_body(
    const void* x,
    const void* Wq, const void* bq,
    const void* Wk, const void* bk,
    const void* Wv, const void* bv,
    const void* ln1w, const void* ln1b,
    float* x1f, bf16* Qb, bf16* Kb, bf16* Vb, float (*xs)[64])
{
  const int w = threadIdx.x >> 6, lane = threadIdx.x & 63;
  const int row = blockIdx.x * 4 + w;                 // 0..8191 (= b*2048+s)
  float xv = ldf<F32>(x, row * 64 + lane);
  float mu = wred_sum(xv) * 0.015625f;
  float dv = xv - mu;
  float var = wred_sum(dv * dv) * 0.015625f;
  float x1 = dv * rsqrtf(var + 1e-5f) * ldf<F32>(ln1w, lane) + ldf<F32>(ln1b, lane);
  x1f[(size_t)row * 64 + lane] = x1;
  xs[w][lane] = x1;
  __syncthreads();
  float q = ldf<F32>(bq, lane);
  float k = ldf<F32>(bk, lane);
  float v = ldf<F32>(bv, lane);
#pragma unroll 16
  for (int d = 0; d < 64; ++d){
    float xd = xs[w][d];                              // LDS broadcast
    q += xd * ldf<F32>(Wq, d * 64 + lane);            // contiguous per d
    k += xd * ldf<F32>(Wk, d * 64 + lane);
    v += xd * ldf<F32>(Wv, d * 64 + lane);
  }
  Qb[(size_t)row * 64 + lane] = __float2bfloat16(q * QSCALE);  // pre-scaled
  Kb[(size_t)row * 64 + lane] = __float2bfloat16(k);
  Vb[(size_t)row * 64 + lane] = __float2bfloat16(v);
}

__global__ __launch_bounds__(256) void k_ln_qkv(
    const void* x, const void* Wq, const void* bq, const void* Wk, const void* bk,
    const void* Wv, const void* bv, const void* ln1w, const void* ln1b,
    float* x1f, bf16* Qb, bf16* Kb, bf16* Vb)
{
  __shared__ float xs[4][64];
  if (detect_f32(x))
    ln_qkv_body<1>(x, Wq, bq, Wk, bk, Wv, bv, ln1w, ln1b, x1f, Qb, Kb, Vb, xs);
  else
    ln_qkv_body<0>(x, Wq, bq, Wk, bk, Wv, bv, ln1w, ln1b, x1f, Qb, Kb, Vb, xs);
}

// ---------------- Kernel A2: transpose V -> Vt[b][h][d][s] (bf16) ----------------
__global__ __launch_bounds__(256) void k_vt(const bf16* __restrict__ Vb, bf16* __restrict__ Vt)
{
  const int idx = blockIdx.x;            // 256 blocks
  const int sc = idx & 7;                // s-chunk (8 x 256)
  const int bh = idx >> 3;               // b*8+h, 0..31
  const int s0 = sc * 256;
  const int b = bh >> 3, h = bh & 7;
  __shared__ unsigned short tile[256][9];   // pad to break bank alignment
  const int t = threadIdx.x;
  s8v vrow = *reinterpret_cast<const s8v*>(Vb + ((size_t)(b * SEQ + s0 + t)) * 64 + h * 8);
#pragma unroll
  for (int i = 0; i < 8; ++i) tile[t][i] = (unsigned short)vrow[i];
  __syncthreads();
  const int d = t >> 5, j = t & 31;      // d 0..7, j 0..31 (8 s-values each)
  unsigned short tmp[8];
#pragma unroll
  for (int i = 0; i < 8; ++i) tmp[i] = tile[j * 8 + i][d];
  uint4 o;
  o.x = (unsigned)tmp[0] | ((unsigned)tmp[1] << 16);
  o.y = (unsigned)tmp[2] | ((unsigned)tmp[3] << 16);
  o.z = (unsigned)tmp[4] | ((unsigned)tmp[5] << 16);
  o.w = (unsigned)tmp[6] | ((unsigned)tmp[7] << 16);
  *reinterpret_cast<uint4*>(Vt + ((size_t)(bh * 8 + d)) * SEQ + s0 + j * 8) = o;
}

// ---------------- Kernel B: flash attention, no barriers, 128-key tiles ----------
// 512 thr (8 waves, wave w = head w); 16 queries per block; waves independent.
// S^T = K_tile . Q^T via mfma_16x16x16_bf16 (dk=8 padded to 16).
// D-layout of S^T (k=4g+i, q=lane&15) == B-operand layout of PV -> no transpose.
__global__ __launch_bounds__(512) void k_attn(
    const bf16* __restrict__ Qb, const bf16* __restrict__ Kb, const bf16* __restrict__ Vt,
    const int* __restrict__ mask, float* __restrict__ ctxf)
{
  const int b  = blockIdx.x >> 7;
  const int q0 = (blockIdx.x & 127) * 16;
  const int h  = threadIdx.x >> 6;
  const int lane = threadIdx.x & 63;
  const int g = lane >> 4, qi = lane & 15;

  s4v qf = {0, 0, 0, 0};
  if (g < 2) qf = *reinterpret_cast<const s4v*>(Qb + ((size_t)(b * SEQ + q0 + qi)) * 64 + h * 8 + 4 * g);

  const bf16* kbase = Kb + (size_t)b * SEQ * 64 + h * 8 + 4 * g;          // deref when g<2
  const bf16* vbase = Vt + ((size_t)((b * 8 + h) * 8 + qi)) * SEQ;        // deref when qi<8
  const int*  mrow  = mask + (size_t)b * SEQ * SEQ + (size_t)(q0 + qi) * SEQ + 4 * g;

  float m_run = -3.0e38f, s_run = 0.f;
  f32x4 acc = {0.f, 0.f, 0.f, 0.f};
  const f32x4 zf = {0.f, 0.f, 0.f, 0.f};

  for (int kt = 0; kt < SEQ / 128; ++kt){
    const int k0 = kt * 128;
    f32x4 st[8];
    int4 mm[8];
#pragma unroll
    for (int hs = 0; hs < 8; ++hs){
      const int kb = k0 + hs * 16;
      mm[hs] = *reinterpret_cast<const int4*>(mrow + kb);
      s4v kf = {0, 0, 0, 0};
      if (g < 2) kf = *reinterpret_cast<const s4v*>(kbase + (size_t)(kb + qi) * 64);
      st[hs] = __builtin_amdgcn_mfma_f32_16x16x16bf16_1k(kf, qf, zf, 0, 0, 0);
    }
    // masked log2-domain scores (scale pre-folded into Q) + tile max
    float tm = -3.0e38f;
#pragma unroll
    for (int hs = 0; hs < 8; ++hs){
      st[hs][0] = (mm[hs].x == 1) ? -1.44e9f : st[hs][0];
      st[hs][1] = (mm[hs].y == 1) ? -1.44e9f : st[hs][1];
      st[hs][2] = (mm[hs].z == 1) ? -1.44e9f : st[hs][2];
      st[hs][3] = (mm[hs].w == 1) ? -1.44e9f : st[hs][3];
      tm = fmaxf(tm, fmaxf(fmaxf(st[hs][0], st[hs][1]), fmaxf(st[hs][2], st[hs][3])));
    }
    tm = fmaxf(tm, __shfl_xor(tm, 16, 64));
    tm = fmaxf(tm, __shfl_xor(tm, 32, 64));
    const float mnew = fmaxf(m_run, tm);
    const float corr = exp2f(m_run - mnew);
    m_run = mnew;

    float ts = 0.f;
    unsigned pw[8][2];
#pragma unroll
    for (int hs = 0; hs < 8; ++hs){
      float p0 = exp2f(st[hs][0] - mnew);
      float p1 = exp2f(st[hs][1] - mnew);
      float p2 = exp2f(st[hs][2] - mnew);
      float p3 = exp2f(st[hs][3] - mnew);
      ts += (p0 + p1) + (p2 + p3);
      asm("v_cvt_pk_bf16_f32 %0, %1, %2" : "=v"(pw[hs][0]) : "v"(p0), "v"(p1));
      asm("v_cvt_pk_bf16_f32 %0, %1, %2" : "=v"(pw[hs][1]) : "v"(p2), "v"(p3));
    }
    ts += __shfl_xor(ts, 16, 64);
    ts += __shfl_xor(ts, 32, 64);
    s_run = s_run * corr + ts;

    acc[0] *= corr; acc[1] *= corr; acc[2] *= corr; acc[3] *= corr;
#pragma unroll
    for (int hs = 0; hs < 8; ++hs){
      s4v vf = {0, 0, 0, 0};
      if (qi < 8) vf = *reinterpret_cast<const s4v*>(vbase + k0 + hs * 16 + 4 * g);
      s4v pf = *reinterpret_cast<s4v*>(&pw[hs][0]);
      acc = __builtin_amdgcn_mfma_f32_16x16x16bf16_1k(vf, pf, acc, 0, 0, 0);
    }
  }
  if (g < 2){
    const float inv = 1.f / s_run;
    float4 o;
    o.x = acc[0] * inv; o.y = acc[1] * inv; o.z = acc[2] * inv; o.w = acc[3] * inv;
    *reinterpret_cast<float4*>(ctxf + ((size_t)((b * 8 + h) * SEQ + q0 + qi)) * 8 + 4 * g) = o;
  }
}

// ---------------- Kernel C: Wo + residuals + LN2 + FFN (wave per row) ----------------
template<int F32>
__device__ __forceinline__ void ffn_body(
    const float* ctxf, const float* x1f,
    const void* Wo, const void* bo, const void* W1, const void* b1,
    const void* W2, const void* b2, const void* ln2w, const void* ln2b,
    void* out, float (*cs)[64], float (*x3s)[64], float (*gs)[256])
{
  const int w = threadIdx.x >> 6, c = threadIdx.x & 63;
  const int row = blockIdx.x * 4 + w;
  // ctx.reshape(B,S,D) of contiguous [B,H,S,dk] == flat view: ctx_resh[b,r,c]=ctxf[row*64+c]
  float ctxv = ctxf[(size_t)row * 64 + c];
  float x1v  = x1f[(size_t)row * 64 + c];
  cs[w][c] = ctxv;
  __syncthreads();
  float proj = ldf<F32>(bo, c);
#pragma unroll 8
  for (int d = 0; d < 64; ++d) proj += cs[w][d] * ldf<F32>(Wo, d * 64 + c);
  // attn_out = ctx@Wo + bo + x1 ; x2 = x1 + attn_out (faithful double residual)
  float x2 = 2.f * x1v + proj;
  float mu = wred_sum(x2) * 0.015625f;
  float dv = x2 - mu;
  float var = wred_sum(dv * dv) * 0.015625f;
  float x3 = dv * rsqrtf(var + 1e-5f) * ldf<F32>(ln2w, c) + ldf<F32>(ln2b, c);
  x3s[w][c] = x3;
  __syncthreads();
#pragma unroll
  for (int cc = 0; cc < 4; ++cc){
    const int col = cc * 64 + c;
    float h1 = ldf<F32>(b1, col);
#pragma unroll 8
    for (int d = 0; d < 64; ++d) h1 += x3s[w][d] * ldf<F32>(W1, d * 256 + col);
    gs[w][col] = 0.5f * h1 * (1.f + erff(h1 * 0.70710678f));   // exact gelu
  }
  __syncthreads();
  float ff = ldf<F32>(b2, c);
#pragma unroll 8
  for (int f = 0; f < 256; ++f) ff += gs[w][f] * ldf<F32>(W2, f * 64 + c);
  float res = x2 + ff;
  if constexpr (F32) ((float*)out)[(size_t)row * 64 + c] = res;
  else               ((bf16*)out)[(size_t)row * 64 + c] = __float2bfloat16(res);
}

__global__ __launch_bounds__(256) void k_ffn(
    const void* xprobe,
    const float* ctxf, const float* x1f,
    const void* Wo, const void* bo, const void* W1, const void* b1,
    const void* W2, const void* b2, const void* ln2w, const void* ln2b,
    void* out)
{
  __shared__ float cs[4][64];
  __shared__ float x3s[4][64];
  __shared__ float gs[4][256];
  if (detect_f32(xprobe))
    ffn_body<1>(ctxf, x1f, Wo, bo, W1, b1, W2, b2, ln2w, ln2b, out, cs, x3s, gs);
  else
    ffn_body<0>(ctxf, x1f, Wo, bo, W1, b1, W2, b2, ln2w, ln2b, out, cs, x3s, gs);
}

extern "C" void kernel_launch(void* const* d_in, const int* in_sizes, int n_in,
                              void* d_out, int out_size, void* d_ws, size_t ws_size,
                              hipStream_t stream)
{
  (void)in_sizes; (void)n_in; (void)out_size; (void)ws_size;
  const void* x    = d_in[0];
  const int*  mask = (const int*)d_in[1];
  const void* Wq = d_in[2];
  const void* bq = d_in[3];
  const void* Wk = d_in[4];
  const void* bk = d_in[5];
  const void* Wv = d_in[6];
  const void* bv = d_in[7];
  const void* Wo = d_in[8];
  const void* bo = d_in[9];
  const void* W1 = d_in[10];
  const void* b1 = d_in[11];
  const void* W2 = d_in[12];
  const void* b2 = d_in[13];
  const void* ln1w = d_in[14];
  const void* ln1b = d_in[15];
  const void* ln2w = d_in[16];
  const void* ln2b = d_in[17];

  char* ws = (char*)d_ws;
  float* x1f = (float*)(ws + 0);              // 2 MB  [B][S][64] f32
  bf16*  Qb  = (bf16*)(ws + (2u << 20));      // 1 MB  [B][S][64] bf16 (pre-scaled)
  bf16*  Kb  = (bf16*)(ws + (3u << 20));      // 1 MB
  bf16*  Vb  = (bf16*)(ws + (4u << 20));      // 1 MB
  bf16*  Vt  = (bf16*)(ws + (5u << 20));      // 1 MB  [B][H][8][S] bf16
  float* ctxf= (float*)(ws + (6u << 20));     // 2 MB  [B][H][S][8] f32

  k_ln_qkv<<<2048, 256, 0, stream>>>(x, Wq, bq, Wk, bk, Wv, bv, ln1w, ln1b, x1f, Qb, Kb, Vb);
  k_vt<<<256, 256, 0, stream>>>(Vb, Vt);
  k_attn<<<512, 512, 0, stream>>>(Qb, Kb, Vt, mask, ctxf);
  k_ffn<<<2048, 256, 0, stream>>>(x, ctxf, x1f, Wo, bo, W1, b1, W2, b2, ln2w, ln2b, d_out);
}

// Round 4
// 171.218 us; speedup vs baseline: 1.1655x; 1.1559x over previous
//
#include <hip/hip_runtime.h>
#include <hip/hip_bf16.h>

#define SEQ 2048

typedef short s4v __attribute__((ext_vector_type(4)));
typedef float f32x4 __attribute__((ext_vector_type(4)));
typedef short s8v __attribute__((ext_vector_type(8)));

using bf16 = __hip_bfloat16;
using ull = unsigned long long;

__device__ __forceinline__ float wred_sum(float v){
#pragma unroll
  for (int i = 1; i < 64; i <<= 1) v += __shfl_xor(v, i, 64);
  return v;
}

__device__ __forceinline__ float wred_max(float v){
#pragma unroll
  for (int i = 1; i < 64; i <<= 1) v = fmaxf(v, __shfl_xor(v, i, 64));
  return v;
}

// Detect whether a "float" input buffer is really f32 (1) or bf16 (0).
__device__ __forceinline__ int detect_f32(const void* xraw){
  const unsigned short* p = (const unsigned short*)xraw;
  const int lane = threadIdx.x & 63;
  float mx = 0.f;
#pragma unroll
  for (int i = 0; i < 2; ++i){
    unsigned u = ((unsigned)p[lane * 2 + i]) << 16;
    float f = fabsf(__uint_as_float(u));
    if (!(f < 1e30f)) f = 1e30f;       // NaN/Inf -> large
    mx = fmaxf(mx, f);
  }
  mx = wred_max(mx);
  return mx > 1e3f ? 1 : 0;
}

template<int F32>
__device__ __forceinline__ float ldf(const void* p, int i){
  if constexpr (F32) return ((const float*)p)[i];
  else return __bfloat162float(((const bf16*)p)[i]);
}

// log2(e)/sqrt(dk) folded into Q at projection time
#define QSCALE 0.5101129340352065f

// ---------------- Kernel P: bit-pack the mask (64 MB int32 -> 2 MB bits) -------
// Wave per row; linear 256B-per-instruction reads; rows parallel across waves so
// addresses spread over all HBM channels. packed[row][w] bit l = (mask[row][w*64+l]==1).
__global__ __launch_bounds__(256) void k_pack(const int* __restrict__ mask, ull* __restrict__ pm)
{
  const int w = threadIdx.x >> 6, lane = threadIdx.x & 63;
  const int row = blockIdx.x * 4 + w;                    // 0..8191 (= b*2048+q)
  const int* rp = mask + (size_t)row * SEQ;
  ull* op = pm + (size_t)row * 32;
#pragma unroll
  for (int it = 0; it < 8; ++it){
    const int c0 = it * 256 + lane;
    ull m0 = __ballot(rp[c0] == 1);
    ull m1 = __ballot(rp[c0 + 64] == 1);
    ull m2 = __ballot(rp[c0 + 128] == 1);
    ull m3 = __ballot(rp[c0 + 192] == 1);
    if (lane == 0){
      op[it * 4 + 0] = m0; op[it * 4 + 1] = m1;
      op[it * 4 + 2] = m2; op[it * 4 + 3] = m3;
    }
  }
}

// ---------------- Kernel A: LN1 + QKV projection (wave per row) ----------------
template<int F32>
__device__ __forceinline__ void ln_qkv_body(
    const void* x,
    const void* Wq, const void* bq,
    const void* Wk, const void* bk,
    const void* Wv, const void* bv,
    const void* ln1w, const void* ln1b,
    float* x1f, bf16* Qb, bf16* Kb, bf16* Vb, float (*xs)[64])
{
  const int w = threadIdx.x >> 6, lane = threadIdx.x & 63;
  const int row = blockIdx.x * 4 + w;                 // 0..8191 (= b*2048+s)
  float xv = ldf<F32>(x, row * 64 + lane);
  float mu = wred_sum(xv) * 0.015625f;
  float dv = xv - mu;
  float var = wred_sum(dv * dv) * 0.015625f;
  float x1 = dv * rsqrtf(var + 1e-5f) * ldf<F32>(ln1w, lane) + ldf<F32>(ln1b, lane);
  x1f[(size_t)row * 64 + lane] = x1;
  xs[w][lane] = x1;
  __syncthreads();
  float q = ldf<F32>(bq, lane);
  float k = ldf<F32>(bk, lane);
  float v = ldf<F32>(bv, lane);
#pragma unroll 16
  for (int d = 0; d < 64; ++d){
    float xd = xs[w][d];                              // LDS broadcast
    q += xd * ldf<F32>(Wq, d * 64 + lane);            // contiguous per d
    k += xd * ldf<F32>(Wk, d * 64 + lane);
    v += xd * ldf<F32>(Wv, d * 64 + lane);
  }
  Qb[(size_t)row * 64 + lane] = __float2bfloat16(q * QSCALE);  // pre-scaled
  Kb[(size_t)row * 64 + lane] = __float2bfloat16(k);
  Vb[(size_t)row * 64 + lane] = __float2bfloat16(v);
}

__global__ __launch_bounds__(256) void k_ln_qkv(
    const void* x, const void* Wq, const void* bq, const void* Wk, const void* bk,
    const void* Wv, const void* bv, const void* ln1w, const void* ln1b,
    float* x1f, bf16* Qb, bf16* Kb, bf16* Vb)
{
  __shared__ float xs[4][64];
  if (detect_f32(x))
    ln_qkv_body<1>(x, Wq, bq, Wk, bk, Wv, bv, ln1w, ln1b, x1f, Qb, Kb, Vb, xs);
  else
    ln_qkv_body<0>(x, Wq, bq, Wk, bk, Wv, bv, ln1w, ln1b, x1f, Qb, Kb, Vb, xs);
}

// ---------------- Kernel A2: transpose V -> Vt[b][h][d][s] (bf16) ----------------
__global__ __launch_bounds__(256) void k_vt(const bf16* __restrict__ Vb, bf16* __restrict__ Vt)
{
  const int idx = blockIdx.x;            // 256 blocks
  const int sc = idx & 7;                // s-chunk (8 x 256)
  const int bh = idx >> 3;               // b*8+h, 0..31
  const int s0 = sc * 256;
  const int b = bh >> 3, h = bh & 7;
  __shared__ unsigned short tile[256][9];   // pad to break bank alignment
  const int t = threadIdx.x;
  s8v vrow = *reinterpret_cast<const s8v*>(Vb + ((size_t)(b * SEQ + s0 + t)) * 64 + h * 8);
#pragma unroll
  for (int i = 0; i < 8; ++i) tile[t][i] = (unsigned short)vrow[i];
  __syncthreads();
  const int d = t >> 5, j = t & 31;      // d 0..7, j 0..31 (8 s-values each)
  unsigned short tmp[8];
#pragma unroll
  for (int i = 0; i < 8; ++i) tmp[i] = tile[j * 8 + i][d];
  uint4 o;
  o.x = (unsigned)tmp[0] | ((unsigned)tmp[1] << 16);
  o.y = (unsigned)tmp[2] | ((unsigned)tmp[3] << 16);
  o.z = (unsigned)tmp[4] | ((unsigned)tmp[5] << 16);
  o.w = (unsigned)tmp[6] | ((unsigned)tmp[7] << 16);
  *reinterpret_cast<uint4*>(Vt + ((size_t)(bh * 8 + d)) * SEQ + s0 + j * 8) = o;
}

// ---------------- Kernel B: flash attention, packed mask, 128-key tiles ----------
// 512 thr (8 waves, wave w = head w); 16 queries per block; waves independent.
// S^T = K_tile . Q^T via mfma_16x16x16_bf16 (dk=8 padded to 16).
// D-layout of S^T (k=4g+i, q=lane&15) == B-operand layout of PV -> no transpose.
__global__ __launch_bounds__(512) void k_attn(
    const bf16* __restrict__ Qb, const bf16* __restrict__ Kb, const bf16* __restrict__ Vt,
    const ull* __restrict__ pm, float* __restrict__ ctxf)
{
  const int b  = blockIdx.x >> 7;
  const int q0 = (blockIdx.x & 127) * 16;
  const int h  = threadIdx.x >> 6;
  const int lane = threadIdx.x & 63;
  const int g = lane >> 4, qi = lane & 15;

  s4v qf = {0, 0, 0, 0};
  if (g < 2) qf = *reinterpret_cast<const s4v*>(Qb + ((size_t)(b * SEQ + q0 + qi)) * 64 + h * 8 + 4 * g);

  const bf16* kbase = Kb + (size_t)b * SEQ * 64 + h * 8 + 4 * g;          // deref when g<2
  const bf16* vbase = Vt + ((size_t)((b * 8 + h) * 8 + qi)) * SEQ;        // deref when qi<8
  const ull*  prow  = pm + (size_t)(b * SEQ + q0 + qi) * 32;              // packed mask row

  float m_run = -3.0e38f, s_run = 0.f;
  f32x4 acc = {0.f, 0.f, 0.f, 0.f};
  const f32x4 zf = {0.f, 0.f, 0.f, 0.f};
  const int sh4 = 4 * g;

  for (int kt = 0; kt < SEQ / 128; ++kt){
    const int k0 = kt * 128;
    ulonglong2 mw = *reinterpret_cast<const ulonglong2*>(prow + kt * 2);  // cols k0..k0+127
    f32x4 st[8];
#pragma unroll
    for (int hs = 0; hs < 8; ++hs){
      const int kb = k0 + hs * 16;
      s4v kf = {0, 0, 0, 0};
      if (g < 2) kf = *reinterpret_cast<const s4v*>(kbase + (size_t)(kb + qi) * 64);
      st[hs] = __builtin_amdgcn_mfma_f32_16x16x16bf16_1k(kf, qf, zf, 0, 0, 0);
    }
    // masked log2-domain scores (scale pre-folded into Q) + tile max
    float tm = -3.0e38f;
#pragma unroll
    for (int hs = 0; hs < 8; ++hs){
      const unsigned b4 = (unsigned)(((hs < 4) ? mw.x : mw.y) >> (16 * (hs & 3) + sh4)) & 0xFu;
      st[hs][0] = (b4 & 1u) ? -1.44e9f : st[hs][0];
      st[hs][1] = (b4 & 2u) ? -1.44e9f : st[hs][1];
      st[hs][2] = (b4 & 4u) ? -1.44e9f : st[hs][2];
      st[hs][3] = (b4 & 8u) ? -1.44e9f : st[hs][3];
      tm = fmaxf(tm, fmaxf(fmaxf(st[hs][0], st[hs][1]), fmaxf(st[hs][2], st[hs][3])));
    }
    tm = fmaxf(tm, __shfl_xor(tm, 16, 64));
    tm = fmaxf(tm, __shfl_xor(tm, 32, 64));
    const float mnew = fmaxf(m_run, tm);
    const float corr = exp2f(m_run - mnew);
    m_run = mnew;

    float ts = 0.f;
    unsigned pw[8][2];
#pragma unroll
    for (int hs = 0; hs < 8; ++hs){
      float p0 = exp2f(st[hs][0] - mnew);
      float p1 = exp2f(st[hs][1] - mnew);
      float p2 = exp2f(st[hs][2] - mnew);
      float p3 = exp2f(st[hs][3] - mnew);
      ts += (p0 + p1) + (p2 + p3);
      asm("v_cvt_pk_bf16_f32 %0, %1, %2" : "=v"(pw[hs][0]) : "v"(p0), "v"(p1));
      asm("v_cvt_pk_bf16_f32 %0, %1, %2" : "=v"(pw[hs][1]) : "v"(p2), "v"(p3));
    }
    ts += __shfl_xor(ts, 16, 64);
    ts += __shfl_xor(ts, 32, 64);
    s_run = s_run * corr + ts;

    acc[0] *= corr; acc[1] *= corr; acc[2] *= corr; acc[3] *= corr;
#pragma unroll
    for (int hs = 0; hs < 8; ++hs){
      s4v vf = {0, 0, 0, 0};
      if (qi < 8) vf = *reinterpret_cast<const s4v*>(vbase + k0 + hs * 16 + 4 * g);
      s4v pf = *reinterpret_cast<s4v*>(&pw[hs][0]);
      acc = __builtin_amdgcn_mfma_f32_16x16x16bf16_1k(vf, pf, acc, 0, 0, 0);
    }
  }
  if (g < 2){
    const float inv = 1.f / s_run;
    float4 o;
    o.x = acc[0] * inv; o.y = acc[1] * inv; o.z = acc[2] * inv; o.w = acc[3] * inv;
    *reinterpret_cast<float4*>(ctxf + ((size_t)((b * 8 + h) * SEQ + q0 + qi)) * 8 + 4 * g) = o;
  }
}

// ---------------- Kernel C: Wo + residuals + LN2 + FFN (wave per row) ----------------
template<int F32>
__device__ __forceinline__ void ffn_body(
    const float* ctxf, const float* x1f,
    const void* Wo, const void* bo, const void* W1, const void* b1,
    const void* W2, const void* b2, const void* ln2w, const void* ln2b,
    void* out, float (*cs)[64], float (*x3s)[64], float (*gs)[256])
{
  const int w = threadIdx.x >> 6, c = threadIdx.x & 63;
  const int row = blockIdx.x * 4 + w;
  // ctx.reshape(B,S,D) of contiguous [B,H,S,dk] == flat view: ctx_resh[b,r,c]=ctxf[row*64+c]
  float ctxv = ctxf[(size_t)row * 64 + c];
  float x1v  = x1f[(size_t)row * 64 + c];
  cs[w][c] = ctxv;
  __syncthreads();
  float proj = ldf<F32>(bo, c);
#pragma unroll 8
  for (int d = 0; d < 64; ++d) proj += cs[w][d] * ldf<F32>(Wo, d * 64 + c);
  // attn_out = ctx@Wo + bo + x1 ; x2 = x1 + attn_out (faithful double residual)
  float x2 = 2.f * x1v + proj;
  float mu = wred_sum(x2) * 0.015625f;
  float dv = x2 - mu;
  float var = wred_sum(dv * dv) * 0.015625f;
  float x3 = dv * rsqrtf(var + 1e-5f) * ldf<F32>(ln2w, c) + ldf<F32>(ln2b, c);
  x3s[w][c] = x3;
  __syncthreads();
#pragma unroll
  for (int cc = 0; cc < 4; ++cc){
    const int col = cc * 64 + c;
    float h1 = ldf<F32>(b1, col);
#pragma unroll 8
    for (int d = 0; d < 64; ++d) h1 += x3s[w][d] * ldf<F32>(W1, d * 256 + col);
    gs[w][col] = 0.5f * h1 * (1.f + erff(h1 * 0.70710678f));   // exact gelu
  }
  __syncthreads();
  float ff = ldf<F32>(b2, c);
#pragma unroll 8
  for (int f = 0; f < 256; ++f) ff += gs[w][f] * ldf<F32>(W2, f * 64 + c);
  float res = x2 + ff;
  if constexpr (F32) ((float*)out)[(size_t)row * 64 + c] = res;
  else               ((bf16*)out)[(size_t)row * 64 + c] = __float2bfloat16(res);
}

__global__ __launch_bounds__(256) void k_ffn(
    const void* xprobe,
    const float* ctxf, const float* x1f,
    const void* Wo, const void* bo, const void* W1, const void* b1,
    const void* W2, const void* b2, const void* ln2w, const void* ln2b,
    void* out)
{
  __shared__ float cs[4][64];
  __shared__ float x3s[4][64];
  __shared__ float gs[4][256];
  if (detect_f32(xprobe))
    ffn_body<1>(ctxf, x1f, Wo, bo, W1, b1, W2, b2, ln2w, ln2b, out, cs, x3s, gs);
  else
    ffn_body<0>(ctxf, x1f, Wo, bo, W1, b1, W2, b2, ln2w, ln2b, out, cs, x3s, gs);
}

extern "C" void kernel_launch(void* const* d_in, const int* in_sizes, int n_in,
                              void* d_out, int out_size, void* d_ws, size_t ws_size,
                              hipStream_t stream)
{
  (void)in_sizes; (void)n_in; (void)out_size; (void)ws_size;
  const void* x    = d_in[0];
  const int*  mask = (const int*)d_in[1];
  const void* Wq = d_in[2];
  const void* bq = d_in[3];
  const void* Wk = d_in[4];
  const void* bk = d_in[5];
  const void* Wv = d_in[6];
  const void* bv = d_in[7];
  const void* Wo = d_in[8];
  const void* bo = d_in[9];
  const void* W1 = d_in[10];
  const void* b1 = d_in[11];
  const void* W2 = d_in[12];
  const void* b2 = d_in[13];
  const void* ln1w = d_in[14];
  const void* ln1b = d_in[15];
  const void* ln2w = d_in[16];
  const void* ln2b = d_in[17];

  char* ws = (char*)d_ws;
  float* x1f = (float*)(ws + 0);              // 2 MB  [B][S][64] f32
  bf16*  Qb  = (bf16*)(ws + (2u << 20));      // 1 MB  [B][S][64] bf16 (pre-scaled)
  bf16*  Kb  = (bf16*)(ws + (3u << 20));      // 1 MB
  bf16*  Vb  = (bf16*)(ws + (4u << 20));      // 1 MB
  bf16*  Vt  = (bf16*)(ws + (5u << 20));      // 1 MB  [B][H][8][S] bf16
  float* ctxf= (float*)(ws + (6u << 20));     // 2 MB  [B][H][S][8] f32
  ull*   pm  = (ull*)(ws + (8u << 20));       // 2 MB  [B*S][32] packed mask bits

  k_pack<<<2048, 256, 0, stream>>>(mask, pm);
  k_ln_qkv<<<2048, 256, 0, stream>>>(x, Wq, bq, Wk, bk, Wv, bv, ln1w, ln1b, x1f, Qb, Kb, Vb);
  k_vt<<<256, 256, 0, stream>>>(Vb, Vt);
  k_attn<<<512, 512, 0, stream>>>(Qb, Kb, Vt, pm, ctxf);
  k_ffn<<<2048, 256, 0, stream>>>(x, ctxf, x1f, Wo, bo, W1, b1, W2, b2, ln2w, ln2b, d_out);
}